// Round 11
// baseline (287.936 us; speedup 1.0000x reference)
//
#include <hip/hip_runtime.h>
#include <hip/hip_bf16.h>

#define S_LEN 2048
#define NH 16
#define HD 64

typedef __attribute__((ext_vector_type(8))) __bf16 bf16x8;
typedef __attribute__((ext_vector_type(16))) float f32x16;

// 0.125 (1/sqrt(64)) * log2(e): folded into Q so softmax uses exp2 directly
#define QSCALE 0.1803368801111204f

static __device__ __forceinline__ ushort f2bf(float f) {
    unsigned int u = __float_as_uint(f);
    u += 0x7fffu + ((u >> 16) & 1u);
    return (ushort)(u >> 16);
}

static __device__ __forceinline__ void gload16(const void* g, void* l) {
    __builtin_amdgcn_global_load_lds(
        (const __attribute__((address_space(1))) unsigned int*)g,
        (__attribute__((address_space(3))) unsigned int*)l, 16, 0, 0);
}
static __device__ __forceinline__ void gload4(const void* g, void* l) {
    __builtin_amdgcn_global_load_lds(
        (const __attribute__((address_space(1))) unsigned int*)g,
        (__attribute__((address_space(3))) unsigned int*)l, 4, 0, 0);
}

static __device__ __forceinline__ unsigned cvtpk_bf16(float lo, float hi) {
    unsigned r;
    asm("v_cvt_pk_bf16_f32 %0, %1, %2" : "=v"(r) : "v"(lo), "v"(hi));
    return r;
}
static __device__ __forceinline__ float exp2_fast(float x) {
    float r;
    asm("v_exp_f32 %0, %1" : "=v"(r) : "v"(x));
    return r;
}

// ---------------------------------------------------------------------------
// K prepass: [B,S,H,D] f32 -> frag-order bf16.  (r2/r7-proven, verbatim)
// 32-key tile granularity: tile32 (kt*2+kh) = 4 contiguous 1KB d-chunk segs.
// ---------------------------------------------------------------------------
__global__ __launch_bounds__(256) void prep_k_kernel(const float* __restrict__ in,
                                                     ushort* __restrict__ out) {
    unsigned t = blockIdx.x * 256u + threadIdx.x;   // 524288 total
    unsigned o = t & 7u;            // d-octet
    unsigned s = (t >> 3) & 2047u;
    unsigned bh = t >> 14;
    unsigned b = bh >> 4, h = bh & 15u;
    const float* src = in + (((size_t)(b * S_LEN) + s) * NH + h) * HD + o * 8;
    float4 x = *(const float4*)src;
    float4 y = *(const float4*)(src + 4);
    union { ushort u[8]; uint4 q; } fu;
    fu.u[0] = f2bf(x.x); fu.u[1] = f2bf(x.y); fu.u[2] = f2bf(x.z); fu.u[3] = f2bf(x.w);
    fu.u[4] = f2bf(y.x); fu.u[5] = f2bf(y.y); fu.u[6] = f2bf(y.z); fu.u[7] = f2bf(y.w);
    unsigned kt = s >> 6, kh = (s >> 5) & 1u, kl = s & 31u;
    unsigned dchunk = o >> 1, ho = o & 1u;
    size_t ci = (((size_t)(bh * 32u + kt) * 2u + kh) * 4u + dchunk) * 64u + kl + 32u * ho;
    *(uint4*)(out + ci * 8u) = fu.q;
}

// ---------------------------------------------------------------------------
// V prepass: [B,S,H,D] f32 -> frag-order V^T bf16.  (r2/r7-proven, verbatim)
// 32-key tile granularity: tile32 (kt*2+kh) = 4 contiguous 1KB (c,nt) segs.
// ---------------------------------------------------------------------------
__global__ __launch_bounds__(256) void prep_v_kernel(const float* __restrict__ in,
                                                     ushort* __restrict__ out) {
    __shared__ float T[64][68];
    const unsigned tid = threadIdx.x;
    const unsigned kt = blockIdx.x, bh = blockIdx.y;
    const unsigned b = bh >> 4, h = bh & 15u;
#pragma unroll
    for (int i = 0; i < 4; ++i) {
        unsigned idx = tid + i * 256u;
        unsigned sl = idx >> 4, d4 = (idx & 15u) * 4u;
        float4 v = *(const float4*)(in + (((size_t)(b * S_LEN) + kt * 64u + sl) * NH + h) * HD + d4);
        *(float4*)&T[sl][d4] = v;
    }
    __syncthreads();
#pragma unroll
    for (int it = 0; it < 2; ++it) {
        unsigned ct = tid + it * 256u;
        unsigned l = ct & 63u, sub = ct >> 6;
        unsigned nt = sub & 1u, c = (sub >> 1) & 1u, kh = sub >> 2;
        unsigned d = (l & 31u) + 32u * nt;
        unsigned kb = kh * 32u + c * 16u + (l >> 5) * 8u;
        union { ushort u[8]; uint4 q; } fu;
#pragma unroll
        for (int j = 0; j < 8; ++j) fu.u[j] = f2bf(T[kb + j][d]);
        *(uint4*)(out + ((size_t)(bh * 32u + kt) * 8u + sub) * 512u + l * 8u) = fu.q;
    }
}

// ---------------------------------------------------------------------------
// Flash attention: 16 waves (4 q-subtiles x 4 key-groups), 1024-thr blocks,
// KBLK=32 tiles, 2 blocks/CU -> 32 waves/CU (100% occupancy). Swapped QK^T,
// POST-MFMA cndmask masking (C-init BANNED), permlane32_swap P-pack
// (r9/r10-proven), frag-order K+V LDS via global_load_lds, double-buffered,
// mask pre-staged once in prologue, vmcnt(0) drain per tile (counted-vmcnt
// with mixed streams BANNED per r9). 4-way kgrp combine: 3 sequential LDS
// accumulate rounds (2-way version proven since r8).
// ---------------------------------------------------------------------------
struct TileMem {
    ushort K[4][2][2048];   // [kgrp][pb] 32 KB
    ushort V[4][2][2048];   // 32 KB
    int    mk[4][512];      // 8 KB: all 16 tiles' masks per kgrp
};
struct CombMem {
    float ob[4][32][64];    // 32 KB
    float lsb[4][64];
    float rls[4][32];
};
union SMemU { TileMem s; CombMem c; };

__global__ __launch_bounds__(1024, 8) void attn_kernel(const float* __restrict__ Qp,
                                                       const ushort* __restrict__ Kws,
                                                       const ushort* __restrict__ Vws,
                                                       const int* __restrict__ maskp,
                                                       float* __restrict__ outp) {
    __shared__ __align__(16) SMemU sm;

    const unsigned tid = threadIdx.x;
    const unsigned wid = tid >> 6;
    const unsigned lane = tid & 63u;
    const unsigned l31 = lane & 31u;
    const unsigned hi = lane >> 5;
    const unsigned qsub = wid & 3u;
    const unsigned kgrp = wid >> 2;

    const unsigned bh = blockIdx.y;
    const unsigned b = bh >> 4, h = bh & 15u;
    const unsigned q0 = blockIdx.x * 128u + qsub * 32u;

    // Q fragments (B-operand of swapped QK^T): lane holds Q[q0+l31][16dc+8hi+j]
    bf16x8 qf[4];
    {
        const float* qb = Qp + (((size_t)(b * S_LEN) + q0 + l31) * NH + h) * HD + hi * 8u;
#pragma unroll
        for (int dc = 0; dc < 4; ++dc) {
            float4 x = *(const float4*)(qb + dc * 16);
            float4 y = *(const float4*)(qb + dc * 16 + 4);
            union { ushort u[8]; bf16x8 v; } fu;
            fu.u[0] = f2bf(x.x * QSCALE); fu.u[1] = f2bf(x.y * QSCALE);
            fu.u[2] = f2bf(x.z * QSCALE); fu.u[3] = f2bf(x.w * QSCALE);
            fu.u[4] = f2bf(y.x * QSCALE); fu.u[5] = f2bf(y.y * QSCALE);
            fu.u[6] = f2bf(y.z * QSCALE); fu.u[7] = f2bf(y.w * QSCALE);
            qf[dc] = fu.v;
        }
    }

    f32x16 oacc0 = {0,0,0,0,0,0,0,0,0,0,0,0,0,0,0,0};
    f32x16 oacc1 = {0,0,0,0,0,0,0,0,0,0,0,0,0,0,0,0};
    float ls0 = 0.f, ls1 = 0.f, ls2 = 0.f, ls3 = 0.f;

    // per-lane staging pointers: kgrp covers 32-key tiles kgrp*16..+15,
    // tile byte stride 4096; qsub wave loads d-chunk/seg #qsub (1KB) of each
    const char* kgp = (const char*)Kws + (size_t)bh * 262144u
                    + (size_t)kgrp * 65536u + qsub * 1024u + lane * 16u;
    const char* vgp = (const char*)Vws + (size_t)bh * 262144u
                    + (size_t)kgrp * 65536u + qsub * 1024u + lane * 16u;

    ushort* klb = &sm.s.K[kgrp][0][qsub * 512u];
    ushort* vlb = &sm.s.V[kgrp][0][qsub * 512u];
    const ushort* krd = &sm.s.K[kgrp][0][0];
    const ushort* vrd = &sm.s.V[kgrp][0][0];

#define STAGE(T, PB) do {                                                      \
    const size_t toff = (size_t)(T) * 4096u;                                   \
    gload16(kgp + toff, klb + (PB) * 2048u);                                   \
    gload16(vgp + toff, vlb + (PB) * 2048u);                                   \
  } while (0)

    // prologue: stage ALL mask ints for this kgrp (512 keys) + first K/V tile
    {
        const int* mg = maskp + (size_t)b * S_LEN + kgrp * 512u + qsub * 128u + lane;
        gload4(mg,      &sm.s.mk[kgrp][qsub * 128u]);
        gload4(mg + 64, &sm.s.mk[kgrp][qsub * 128u + 64u]);
    }
    STAGE(0, 0u);
    asm volatile("s_waitcnt vmcnt(0)" ::: "memory");
    __syncthreads();

    unsigned pb = 0;
    for (int t = 0; t < 16; ++t) {
        if (t < 15) STAGE(t + 1, pb ^ 1u);
        const ushort* kr = krd + pb * 2048u;
        const ushort* vr = vrd + pb * 2048u;
        const int*    mr = &sm.s.mk[kgrp][(unsigned)t * 32u];

        bf16x8 kf[4];
#pragma unroll
        for (int dc = 0; dc < 4; ++dc)
            kf[dc] = *(const bf16x8*)&kr[dc * 512u + lane * 8u];

        f32x16 s = {0,0,0,0,0,0,0,0,0,0,0,0,0,0,0,0};
        __builtin_amdgcn_s_setprio(1);
#pragma unroll
        for (int dc = 0; dc < 4; ++dc)
            s = __builtin_amdgcn_mfma_f32_32x32x16_bf16(kf[dc], qf[dc], s, 0, 0, 0);
        __builtin_amdgcn_s_setprio(0);

        // mask post-MFMA (r7-proven): masked keys -> exp2(-1e30) = 0
        float p[16];
#pragma unroll
        for (int r1 = 0; r1 < 4; ++r1) {
            int mv[4];
            *(int4*)mv = *(const int4*)&mr[r1 * 8 + hi * 4];
#pragma unroll
            for (int r0 = 0; r0 < 4; ++r0) {
                const int reg = r1 * 4 + r0;
                float tt = mv[r0] ? s[reg] : -1e30f;
                p[reg] = exp2_fast(tt);
            }
            ls0 += p[r1 * 4 + 0]; ls1 += p[r1 * 4 + 1];
            ls2 += p[r1 * 4 + 2]; ls3 += p[r1 * 4 + 3];
        }

        // pack P -> PV A-frags: cvt_pk + permlane32_swap (r9/r10-proven)
#pragma unroll
        for (int c = 0; c < 2; ++c) {
            unsigned a0 = cvtpk_bf16(p[8 * c + 0], p[8 * c + 1]);
            unsigned a1 = cvtpk_bf16(p[8 * c + 2], p[8 * c + 3]);
            unsigned b0 = cvtpk_bf16(p[8 * c + 4], p[8 * c + 5]);
            unsigned b1 = cvtpk_bf16(p[8 * c + 6], p[8 * c + 7]);
            asm("v_permlane32_swap_b32 %0, %1" : "+v"(a0), "+v"(b0));
            asm("v_permlane32_swap_b32 %0, %1" : "+v"(a1), "+v"(b1));
            union { unsigned w[4]; bf16x8 v; } pa;
            pa.w[0] = a0; pa.w[1] = a1; pa.w[2] = b0; pa.w[3] = b1;
            bf16x8 vf0 = *(const bf16x8*)&vr[(c * 2 + 0) * 512u + lane * 8u];
            bf16x8 vf1 = *(const bf16x8*)&vr[(c * 2 + 1) * 512u + lane * 8u];
            __builtin_amdgcn_s_setprio(1);
            oacc0 = __builtin_amdgcn_mfma_f32_32x32x16_bf16(pa.v, vf0, oacc0, 0, 0, 0);
            oacc1 = __builtin_amdgcn_mfma_f32_32x32x16_bf16(pa.v, vf1, oacc1, 0, 0, 0);
            __builtin_amdgcn_s_setprio(0);
        }

        asm volatile("s_waitcnt vmcnt(0)" ::: "memory");
        __syncthreads();
        pb ^= 1u;
    }
#undef STAGE

    // denominator: lane's rows + xor-32 partner's rows = kgrp's 512 keys
    float lsum = (ls0 + ls1) + (ls2 + ls3);
    lsum += __shfl_xor(lsum, 32);

    // ---- 4-way kgrp combine: 3 sequential LDS accumulate rounds ----
    // (loop's final barrier guarantees all K/V reads retired before overlay)
    if (kgrp == 3) {
#pragma unroll
        for (int r = 0; r < 16; ++r) {
            sm.c.ob[qsub][r][lane]      = oacc0[r];
            sm.c.ob[qsub][16 + r][lane] = oacc1[r];
        }
        sm.c.lsb[qsub][lane] = lsum;
    }
    __syncthreads();
    if (kgrp == 2) {
#pragma unroll
        for (int r = 0; r < 16; ++r) {
            sm.c.ob[qsub][r][lane]      += oacc0[r];
            sm.c.ob[qsub][16 + r][lane] += oacc1[r];
        }
        sm.c.lsb[qsub][lane] += lsum;
    }
    __syncthreads();
    if (kgrp == 1) {
#pragma unroll
        for (int r = 0; r < 16; ++r) {
            sm.c.ob[qsub][r][lane]      += oacc0[r];
            sm.c.ob[qsub][16 + r][lane] += oacc1[r];
        }
        sm.c.lsb[qsub][lane] += lsum;
    }
    __syncthreads();
    if (kgrp == 0) {
        lsum += sm.c.lsb[qsub][lane];
#pragma unroll
        for (int r = 0; r < 16; ++r) {
            oacc0[r] += sm.c.ob[qsub][r][lane];
            oacc1[r] += sm.c.ob[qsub][16 + r][lane];
        }
        if (hi == 0) sm.c.rls[qsub][l31] = 1.0f / lsum;
#pragma unroll
        for (int r1 = 0; r1 < 4; ++r1) {
#pragma unroll
            for (int r0 = 0; r0 < 4; ++r0) {
                const int reg = r1 * 4 + r0;
                const unsigned q = r0 + 8u * r1 + 4u * hi;
                const float rr = sm.c.rls[qsub][q];
                float* ob = outp + (((size_t)(b * S_LEN) + q0 + q) * NH + h) * HD + l31;
                ob[0]  = oacc0[reg] * rr;
                ob[32] = oacc1[reg] * rr;
            }
        }
    }
}

extern "C" void kernel_launch(void* const* d_in, const int* in_sizes, int n_in,
                              void* d_out, int out_size, void* d_ws, size_t ws_size,
                              hipStream_t stream) {
    const float* Qp = (const float*)d_in[0];
    const float* Kp = (const float*)d_in[1];
    const float* Vp = (const float*)d_in[2];
    const int* maskp = (const int*)d_in[3];
    float* outp = (float*)d_out;

    ushort* Kws = (ushort*)d_ws;                              // 8.39 MB frag-order K
    ushort* Vws = Kws + (size_t)2 * NH * S_LEN * HD;          // 8.39 MB frag-order V^T

    hipLaunchKernelGGL(prep_k_kernel, dim3(2048), dim3(256), 0, stream, Kp, Kws);
    hipLaunchKernelGGL(prep_v_kernel, dim3(32, 32), dim3(256), 0, stream, Vp, Vws);
    hipLaunchKernelGGL(attn_kernel, dim3(S_LEN / 128, 32), dim3(1024), 0, stream,
                       Qp, Kws, Vws, maskp, outp);
}

// Round 12
// 179.059 us; speedup vs baseline: 1.6081x; 1.6081x over previous
//
#include <hip/hip_runtime.h>
#include <hip/hip_bf16.h>

#define S_LEN 2048
#define NH 16
#define HD 64

typedef __attribute__((ext_vector_type(8))) __bf16 bf16x8;
typedef __attribute__((ext_vector_type(16))) float f32x16;

// 0.125 (1/sqrt(64)) * log2(e): folded into Q so softmax uses exp2 directly
#define QSCALE 0.1803368801111204f

static __device__ __forceinline__ ushort f2bf(float f) {
    unsigned int u = __float_as_uint(f);
    u += 0x7fffu + ((u >> 16) & 1u);
    return (ushort)(u >> 16);
}

static __device__ __forceinline__ void gload16(const void* g, void* l) {
    __builtin_amdgcn_global_load_lds(
        (const __attribute__((address_space(1))) unsigned int*)g,
        (__attribute__((address_space(3))) unsigned int*)l, 16, 0, 0);
}

static __device__ __forceinline__ unsigned cvtpk_bf16(float lo, float hi) {
    unsigned r;
    asm("v_cvt_pk_bf16_f32 %0, %1, %2" : "=v"(r) : "v"(lo), "v"(hi));
    return r;
}
static __device__ __forceinline__ float exp2_fast(float x) {
    float r;
    asm("v_exp_f32 %0, %1" : "=v"(r) : "v"(x));
    return r;
}

// ---------------------------------------------------------------------------
// K prepass: [B,S,H,D] f32 -> frag-order bf16.  (r2/r7-proven, verbatim)
// 32-key tile granularity: tile32 j = kt*2+kh at byte j*4096 (4 x 1KB segs).
// ---------------------------------------------------------------------------
__global__ __launch_bounds__(256) void prep_k_kernel(const float* __restrict__ in,
                                                     ushort* __restrict__ out) {
    unsigned t = blockIdx.x * 256u + threadIdx.x;   // 524288 total
    unsigned o = t & 7u;            // d-octet
    unsigned s = (t >> 3) & 2047u;
    unsigned bh = t >> 14;
    unsigned b = bh >> 4, h = bh & 15u;
    const float* src = in + (((size_t)(b * S_LEN) + s) * NH + h) * HD + o * 8;
    float4 x = *(const float4*)src;
    float4 y = *(const float4*)(src + 4);
    union { ushort u[8]; uint4 q; } fu;
    fu.u[0] = f2bf(x.x); fu.u[1] = f2bf(x.y); fu.u[2] = f2bf(x.z); fu.u[3] = f2bf(x.w);
    fu.u[4] = f2bf(y.x); fu.u[5] = f2bf(y.y); fu.u[6] = f2bf(y.z); fu.u[7] = f2bf(y.w);
    unsigned kt = s >> 6, kh = (s >> 5) & 1u, kl = s & 31u;
    unsigned dchunk = o >> 1, ho = o & 1u;
    size_t ci = (((size_t)(bh * 32u + kt) * 2u + kh) * 4u + dchunk) * 64u + kl + 32u * ho;
    *(uint4*)(out + ci * 8u) = fu.q;
}

// ---------------------------------------------------------------------------
// V prepass: [B,S,H,D] f32 -> frag-order V^T bf16.  (r2/r7-proven, verbatim)
// tile32 j at byte j*4096; 4 segs (c*2+nt) of 1KB.
// ---------------------------------------------------------------------------
__global__ __launch_bounds__(256) void prep_v_kernel(const float* __restrict__ in,
                                                     ushort* __restrict__ out) {
    __shared__ float T[64][68];
    const unsigned tid = threadIdx.x;
    const unsigned kt = blockIdx.x, bh = blockIdx.y;
    const unsigned b = bh >> 4, h = bh & 15u;
#pragma unroll
    for (int i = 0; i < 4; ++i) {
        unsigned idx = tid + i * 256u;
        unsigned sl = idx >> 4, d4 = (idx & 15u) * 4u;
        float4 v = *(const float4*)(in + (((size_t)(b * S_LEN) + kt * 64u + sl) * NH + h) * HD + d4);
        *(float4*)&T[sl][d4] = v;
    }
    __syncthreads();
#pragma unroll
    for (int it = 0; it < 2; ++it) {
        unsigned ct = tid + it * 256u;
        unsigned l = ct & 63u, sub = ct >> 6;
        unsigned nt = sub & 1u, c = (sub >> 1) & 1u, kh = sub >> 2;
        unsigned d = (l & 31u) + 32u * nt;
        unsigned kb = kh * 32u + c * 16u + (l >> 5) * 8u;
        union { ushort u[8]; uint4 q; } fu;
#pragma unroll
        for (int j = 0; j < 8; ++j) fu.u[j] = f2bf(T[kb + j][d]);
        *(uint4*)(out + ((size_t)(bh * 32u + kt) * 8u + sub) * 512u + l * 8u) = fu.q;
    }
}

// ---------------------------------------------------------------------------
// Flash attention: 1024 blocks x 8 waves (2 q-subtiles x 4 key-groups),
// KBLK=32, 64 q-rows/block. K double-buffered in 32KB LDS (gload_lds);
// V + mask DIRECT global->register (frag-order ws / L1-hot mask) -- safe
// with the vmcnt(0)-per-tile drain (r9's counted-vmcnt mechanism absent).
// permlane32_swap P-pack, post-MFMA cndmask (C-init BANNED), 4-way kgrp
// combine (r11-proven-correct). launch_bounds(512,6): VGPR cap 85 -- the
// r11 allocator meltdown (cap 64 -> 32 VGPR + 600MB scratch) is BANNED.
// Target: 8192 waves = 24-32 waves/CU.
// ---------------------------------------------------------------------------
struct TileMem {
    ushort K[4][2][2048];   // [kgrp][pb] 32 KB
};
struct CombMem {
    float ob[2][32][64];    // 16 KB
    float lsb[2][64];
    float rls[2][32];
};
union SMemU { TileMem s; CombMem c; };

__global__ __launch_bounds__(512, 6) void attn_kernel(const float* __restrict__ Qp,
                                                      const ushort* __restrict__ Kws,
                                                      const ushort* __restrict__ Vws,
                                                      const int* __restrict__ maskp,
                                                      float* __restrict__ outp) {
    __shared__ __align__(16) SMemU sm;

    const unsigned tid = threadIdx.x;
    const unsigned wid = tid >> 6;
    const unsigned lane = tid & 63u;
    const unsigned l31 = lane & 31u;
    const unsigned hi = lane >> 5;
    const unsigned qsub = wid & 1u;
    const unsigned kgrp = wid >> 1;

    const unsigned bh = blockIdx.y;
    const unsigned b = bh >> 4, h = bh & 15u;
    const unsigned q0 = blockIdx.x * 64u + qsub * 32u;

    // Q fragments (B-operand of swapped QK^T): lane holds Q[q0+l31][16dc+8hi+j]
    bf16x8 qf[4];
    {
        const float* qb = Qp + (((size_t)(b * S_LEN) + q0 + l31) * NH + h) * HD + hi * 8u;
#pragma unroll
        for (int dc = 0; dc < 4; ++dc) {
            float4 x = *(const float4*)(qb + dc * 16);
            float4 y = *(const float4*)(qb + dc * 16 + 4);
            union { ushort u[8]; bf16x8 v; } fu;
            fu.u[0] = f2bf(x.x * QSCALE); fu.u[1] = f2bf(x.y * QSCALE);
            fu.u[2] = f2bf(x.z * QSCALE); fu.u[3] = f2bf(x.w * QSCALE);
            fu.u[4] = f2bf(y.x * QSCALE); fu.u[5] = f2bf(y.y * QSCALE);
            fu.u[6] = f2bf(y.z * QSCALE); fu.u[7] = f2bf(y.w * QSCALE);
            qf[dc] = fu.v;
        }
    }

    f32x16 oacc0 = {0,0,0,0,0,0,0,0,0,0,0,0,0,0,0,0};
    f32x16 oacc1 = {0,0,0,0,0,0,0,0,0,0,0,0,0,0,0,0};
    float ls0 = 0.f, ls1 = 0.f, ls2 = 0.f, ls3 = 0.f;

    // K staging: kgrp covers tile32s kgrp*16..+15 (byte stride 4096); wave
    // qsub stages segs {2qsub, 2qsub+1} (1KB each) of each tile.
    const char* kgp = (const char*)Kws + (size_t)bh * 262144u
                    + (size_t)kgrp * 65536u + (2u * qsub) * 1024u + lane * 16u;
    // V direct-read base (ushort units): bh 131072, kgrp 32768, tile 2048
    const ushort* vg = Vws + (size_t)bh * 131072u + (size_t)kgrp * 32768u + lane * 8u;
    // mask direct-read base (int units)
    const int* mg = maskp + (size_t)b * S_LEN + kgrp * 512u;

    ushort* klb = &sm.s.K[kgrp][0][2u * qsub * 512u];
    const ushort* krd = &sm.s.K[kgrp][0][0];

#define STAGE(T, PB) do {                                                      \
    const size_t toff = (size_t)(T) * 4096u;                                   \
    gload16(kgp + toff,          klb + (PB) * 2048u);                          \
    gload16(kgp + toff + 1024u,  klb + (PB) * 2048u + 512u);                   \
  } while (0)

    STAGE(0, 0u);
    asm volatile("s_waitcnt vmcnt(0)" ::: "memory");
    __syncthreads();

    unsigned pb = 0;
    for (int t = 0; t < 16; ++t) {
        if (t < 15) STAGE(t + 1, pb ^ 1u);
        const ushort* kr = krd + pb * 2048u;
        const ushort* vt = vg + (unsigned)t * 2048u;
        const int*    mt = mg + t * 32;

        bf16x8 kf[4];
#pragma unroll
        for (int dc = 0; dc < 4; ++dc)
            kf[dc] = *(const bf16x8*)&kr[dc * 512u + lane * 8u];

        f32x16 s = {0,0,0,0,0,0,0,0,0,0,0,0,0,0,0,0};
        __builtin_amdgcn_s_setprio(1);
#pragma unroll
        for (int dc = 0; dc < 4; ++dc)
            s = __builtin_amdgcn_mfma_f32_32x32x16_bf16(kf[dc], qf[dc], s, 0, 0, 0);
        __builtin_amdgcn_s_setprio(0);

        // mask post-MFMA (r7-proven), direct int4 loads (L1-hot 8KB region)
        float p[16];
#pragma unroll
        for (int r1 = 0; r1 < 4; ++r1) {
            int4 mv = *(const int4*)(mt + r1 * 8 + hi * 4);
            p[r1 * 4 + 0] = exp2_fast(mv.x ? s[r1 * 4 + 0] : -1e30f);
            p[r1 * 4 + 1] = exp2_fast(mv.y ? s[r1 * 4 + 1] : -1e30f);
            p[r1 * 4 + 2] = exp2_fast(mv.z ? s[r1 * 4 + 2] : -1e30f);
            p[r1 * 4 + 3] = exp2_fast(mv.w ? s[r1 * 4 + 3] : -1e30f);
            ls0 += p[r1 * 4 + 0]; ls1 += p[r1 * 4 + 1];
            ls2 += p[r1 * 4 + 2]; ls3 += p[r1 * 4 + 3];
        }

        // pack P -> PV A-frags: cvt_pk + permlane32_swap (r9/r10-proven)
#pragma unroll
        for (int c = 0; c < 2; ++c) {
            unsigned a0 = cvtpk_bf16(p[8 * c + 0], p[8 * c + 1]);
            unsigned a1 = cvtpk_bf16(p[8 * c + 2], p[8 * c + 3]);
            unsigned b0 = cvtpk_bf16(p[8 * c + 4], p[8 * c + 5]);
            unsigned b1 = cvtpk_bf16(p[8 * c + 6], p[8 * c + 7]);
            asm("v_permlane32_swap_b32 %0, %1" : "+v"(a0), "+v"(b0));
            asm("v_permlane32_swap_b32 %0, %1" : "+v"(a1), "+v"(b1));
            union { unsigned w[4]; bf16x8 v; } pa;
            pa.w[0] = a0; pa.w[1] = a1; pa.w[2] = b0; pa.w[3] = b1;
            // V fragments: direct global reads (frag-order, L2/L3-hot)
            bf16x8 vf0 = *(const bf16x8*)(vt + (c * 2 + 0) * 512u);
            bf16x8 vf1 = *(const bf16x8*)(vt + (c * 2 + 1) * 512u);
            __builtin_amdgcn_s_setprio(1);
            oacc0 = __builtin_amdgcn_mfma_f32_32x32x16_bf16(pa.v, vf0, oacc0, 0, 0, 0);
            oacc1 = __builtin_amdgcn_mfma_f32_32x32x16_bf16(pa.v, vf1, oacc1, 0, 0, 0);
            __builtin_amdgcn_s_setprio(0);
        }

        asm volatile("s_waitcnt vmcnt(0)" ::: "memory");
        __syncthreads();
        pb ^= 1u;
    }
#undef STAGE

    // denominator: lane's 16 rows + xor-32 partner's rows = tile's 32 keys
    float lsum = (ls0 + ls1) + (ls2 + ls3);
    lsum += __shfl_xor(lsum, 32);

    // ---- 4-way kgrp combine (r11-proven-correct), overlaying K LDS ----
    if (kgrp == 3) {
#pragma unroll
        for (int r = 0; r < 16; ++r) {
            sm.c.ob[qsub][r][lane]      = oacc0[r];
            sm.c.ob[qsub][16 + r][lane] = oacc1[r];
        }
        sm.c.lsb[qsub][lane] = lsum;
    }
    __syncthreads();
    if (kgrp == 2) {
#pragma unroll
        for (int r = 0; r < 16; ++r) {
            sm.c.ob[qsub][r][lane]      += oacc0[r];
            sm.c.ob[qsub][16 + r][lane] += oacc1[r];
        }
        sm.c.lsb[qsub][lane] += lsum;
    }
    __syncthreads();
    if (kgrp == 1) {
#pragma unroll
        for (int r = 0; r < 16; ++r) {
            sm.c.ob[qsub][r][lane]      += oacc0[r];
            sm.c.ob[qsub][16 + r][lane] += oacc1[r];
        }
        sm.c.lsb[qsub][lane] += lsum;
    }
    __syncthreads();
    if (kgrp == 0) {
        lsum += sm.c.lsb[qsub][lane];
#pragma unroll
        for (int r = 0; r < 16; ++r) {
            oacc0[r] += sm.c.ob[qsub][r][lane];
            oacc1[r] += sm.c.ob[qsub][16 + r][lane];
        }
        if (hi == 0) sm.c.rls[qsub][l31] = 1.0f / lsum;
#pragma unroll
        for (int r1 = 0; r1 < 4; ++r1) {
#pragma unroll
            for (int r0 = 0; r0 < 4; ++r0) {
                const int reg = r1 * 4 + r0;
                const unsigned q = r0 + 8u * r1 + 4u * hi;
                const float rr = sm.c.rls[qsub][q];
                float* ob = outp + (((size_t)(b * S_LEN) + q0 + q) * NH + h) * HD + l31;
                ob[0]  = oacc0[reg] * rr;
                ob[32] = oacc1[reg] * rr;
            }
        }
    }
}

extern "C" void kernel_launch(void* const* d_in, const int* in_sizes, int n_in,
                              void* d_out, int out_size, void* d_ws, size_t ws_size,
                              hipStream_t stream) {
    const float* Qp = (const float*)d_in[0];
    const float* Kp = (const float*)d_in[1];
    const float* Vp = (const float*)d_in[2];
    const int* maskp = (const int*)d_in[3];
    float* outp = (float*)d_out;

    ushort* Kws = (ushort*)d_ws;                              // 8.39 MB frag-order K
    ushort* Vws = Kws + (size_t)2 * NH * S_LEN * HD;          // 8.39 MB frag-order V^T

    hipLaunchKernelGGL(prep_k_kernel, dim3(2048), dim3(256), 0, stream, Kp, Kws);
    hipLaunchKernelGGL(prep_v_kernel, dim3(32, 32), dim3(256), 0, stream, Vp, Vws);
    hipLaunchKernelGGL(attn_kernel, dim3(S_LEN / 64, 32), dim3(512), 0, stream,
                       Qp, Kws, Vws, maskp, outp);
}

// Round 13
// 88.092 us; speedup vs baseline: 3.2686x; 2.0326x over previous
//
#include <hip/hip_runtime.h>
#include <hip/hip_bf16.h>

#define S_LEN 2048
#define NH 16
#define HD 64

typedef __attribute__((ext_vector_type(8))) __bf16 bf16x8;
typedef __attribute__((ext_vector_type(16))) float f32x16;

// 0.125 (1/sqrt(64)) * log2(e): folded into Q so softmax uses exp2 directly
#define QSCALE 0.1803368801111204f

static __device__ __forceinline__ ushort f2bf(float f) {
    unsigned int u = __float_as_uint(f);
    u += 0x7fffu + ((u >> 16) & 1u);
    return (ushort)(u >> 16);
}

static __device__ __forceinline__ void gload16(const void* g, void* l) {
    __builtin_amdgcn_global_load_lds(
        (const __attribute__((address_space(1))) unsigned int*)g,
        (__attribute__((address_space(3))) unsigned int*)l, 16, 0, 0);
}

static __device__ __forceinline__ unsigned cvtpk_bf16(float lo, float hi) {
    unsigned r;
    asm("v_cvt_pk_bf16_f32 %0, %1, %2" : "=v"(r) : "v"(lo), "v"(hi));
    return r;
}
static __device__ __forceinline__ float exp2_fast(float x) {
    float r;
    asm("v_exp_f32 %0, %1" : "=v"(r) : "v"(x));
    return r;
}

// ---------------------------------------------------------------------------
// K prepass: [B,S,H,D] f32 -> frag-order bf16.  (r2/r7-proven, verbatim)
// 32-key tile granularity: tile32 j = kt*2+kh at byte j*4096 (4 x 1KB segs).
// ---------------------------------------------------------------------------
__global__ __launch_bounds__(256) void prep_k_kernel(const float* __restrict__ in,
                                                     ushort* __restrict__ out) {
    unsigned t = blockIdx.x * 256u + threadIdx.x;   // 524288 total
    unsigned o = t & 7u;            // d-octet
    unsigned s = (t >> 3) & 2047u;
    unsigned bh = t >> 14;
    unsigned b = bh >> 4, h = bh & 15u;
    const float* src = in + (((size_t)(b * S_LEN) + s) * NH + h) * HD + o * 8;
    float4 x = *(const float4*)src;
    float4 y = *(const float4*)(src + 4);
    union { ushort u[8]; uint4 q; } fu;
    fu.u[0] = f2bf(x.x); fu.u[1] = f2bf(x.y); fu.u[2] = f2bf(x.z); fu.u[3] = f2bf(x.w);
    fu.u[4] = f2bf(y.x); fu.u[5] = f2bf(y.y); fu.u[6] = f2bf(y.z); fu.u[7] = f2bf(y.w);
    unsigned kt = s >> 6, kh = (s >> 5) & 1u, kl = s & 31u;
    unsigned dchunk = o >> 1, ho = o & 1u;
    size_t ci = (((size_t)(bh * 32u + kt) * 2u + kh) * 4u + dchunk) * 64u + kl + 32u * ho;
    *(uint4*)(out + ci * 8u) = fu.q;
}

// ---------------------------------------------------------------------------
// V prepass: [B,S,H,D] f32 -> frag-order V^T bf16.  (r2/r7-proven, verbatim)
// tile32 j at byte j*4096; 4 segs (c*2+nt) of 1KB.
// ---------------------------------------------------------------------------
__global__ __launch_bounds__(256) void prep_v_kernel(const float* __restrict__ in,
                                                     ushort* __restrict__ out) {
    __shared__ float T[64][68];
    const unsigned tid = threadIdx.x;
    const unsigned kt = blockIdx.x, bh = blockIdx.y;
    const unsigned b = bh >> 4, h = bh & 15u;
#pragma unroll
    for (int i = 0; i < 4; ++i) {
        unsigned idx = tid + i * 256u;
        unsigned sl = idx >> 4, d4 = (idx & 15u) * 4u;
        float4 v = *(const float4*)(in + (((size_t)(b * S_LEN) + kt * 64u + sl) * NH + h) * HD + d4);
        *(float4*)&T[sl][d4] = v;
    }
    __syncthreads();
#pragma unroll
    for (int it = 0; it < 2; ++it) {
        unsigned ct = tid + it * 256u;
        unsigned l = ct & 63u, sub = ct >> 6;
        unsigned nt = sub & 1u, c = (sub >> 1) & 1u, kh = sub >> 2;
        unsigned d = (l & 31u) + 32u * nt;
        unsigned kb = kh * 32u + c * 16u + (l >> 5) * 8u;
        union { ushort u[8]; uint4 q; } fu;
#pragma unroll
        for (int j = 0; j < 8; ++j) fu.u[j] = f2bf(T[kb + j][d]);
        *(uint4*)(out + ((size_t)(bh * 32u + kt) * 8u + sub) * 512u + l * 8u) = fu.q;
    }
}

// ---------------------------------------------------------------------------
// Flash attention: 1024 blocks x 8 waves (2 q-subtiles x 4 key-groups),
// KBLK=32, 64 q-rows/block. K double-buffered in 32KB LDS (gload_lds);
// V + mask DIRECT global->register. permlane32_swap P-pack, post-MFMA
// cndmask (C-init BANNED), 4-way kgrp combine (r11-proven-correct).
// SINGLE CHANGE vs r12: __launch_bounds__(512,4). (512,6) and (1024,8)
// both triggered allocator meltdown (VGPR 40/32 + 75-600MB scratch) --
// min-waves/EU >= 6 on this body is BANNED. (512,4) is r10-proven (60 VGPR,
// no spill). Occupancy then = min(VGPR-limit, LDS 32KB -> 5 blk, grid 4/CU).
// ---------------------------------------------------------------------------
struct TileMem {
    ushort K[4][2][2048];   // [kgrp][pb] 32 KB
};
struct CombMem {
    float ob[2][32][64];    // 16 KB
    float lsb[2][64];
    float rls[2][32];
};
union SMemU { TileMem s; CombMem c; };

__global__ __launch_bounds__(512, 4) void attn_kernel(const float* __restrict__ Qp,
                                                      const ushort* __restrict__ Kws,
                                                      const ushort* __restrict__ Vws,
                                                      const int* __restrict__ maskp,
                                                      float* __restrict__ outp) {
    __shared__ __align__(16) SMemU sm;

    const unsigned tid = threadIdx.x;
    const unsigned wid = tid >> 6;
    const unsigned lane = tid & 63u;
    const unsigned l31 = lane & 31u;
    const unsigned hi = lane >> 5;
    const unsigned qsub = wid & 1u;
    const unsigned kgrp = wid >> 1;

    const unsigned bh = blockIdx.y;
    const unsigned b = bh >> 4, h = bh & 15u;
    const unsigned q0 = blockIdx.x * 64u + qsub * 32u;

    // Q fragments (B-operand of swapped QK^T): lane holds Q[q0+l31][16dc+8hi+j]
    bf16x8 qf[4];
    {
        const float* qb = Qp + (((size_t)(b * S_LEN) + q0 + l31) * NH + h) * HD + hi * 8u;
#pragma unroll
        for (int dc = 0; dc < 4; ++dc) {
            float4 x = *(const float4*)(qb + dc * 16);
            float4 y = *(const float4*)(qb + dc * 16 + 4);
            union { ushort u[8]; bf16x8 v; } fu;
            fu.u[0] = f2bf(x.x * QSCALE); fu.u[1] = f2bf(x.y * QSCALE);
            fu.u[2] = f2bf(x.z * QSCALE); fu.u[3] = f2bf(x.w * QSCALE);
            fu.u[4] = f2bf(y.x * QSCALE); fu.u[5] = f2bf(y.y * QSCALE);
            fu.u[6] = f2bf(y.z * QSCALE); fu.u[7] = f2bf(y.w * QSCALE);
            qf[dc] = fu.v;
        }
    }

    f32x16 oacc0 = {0,0,0,0,0,0,0,0,0,0,0,0,0,0,0,0};
    f32x16 oacc1 = {0,0,0,0,0,0,0,0,0,0,0,0,0,0,0,0};
    float ls0 = 0.f, ls1 = 0.f, ls2 = 0.f, ls3 = 0.f;

    // K staging: kgrp covers tile32s kgrp*16..+15 (byte stride 4096); wave
    // qsub stages segs {2qsub, 2qsub+1} (1KB each) of each tile.
    const char* kgp = (const char*)Kws + (size_t)bh * 262144u
                    + (size_t)kgrp * 65536u + (2u * qsub) * 1024u + lane * 16u;
    // V direct-read base (ushort units): bh 131072, kgrp 32768, tile 2048
    const ushort* vg = Vws + (size_t)bh * 131072u + (size_t)kgrp * 32768u + lane * 8u;
    // mask direct-read base (int units)
    const int* mg = maskp + (size_t)b * S_LEN + kgrp * 512u;

    ushort* klb = &sm.s.K[kgrp][0][2u * qsub * 512u];
    const ushort* krd = &sm.s.K[kgrp][0][0];

#define STAGE(T, PB) do {                                                      \
    const size_t toff = (size_t)(T) * 4096u;                                   \
    gload16(kgp + toff,          klb + (PB) * 2048u);                          \
    gload16(kgp + toff + 1024u,  klb + (PB) * 2048u + 512u);                   \
  } while (0)

    STAGE(0, 0u);
    asm volatile("s_waitcnt vmcnt(0)" ::: "memory");
    __syncthreads();

    unsigned pb = 0;
    for (int t = 0; t < 16; ++t) {
        if (t < 15) STAGE(t + 1, pb ^ 1u);
        const ushort* kr = krd + pb * 2048u;
        const ushort* vt = vg + (unsigned)t * 2048u;
        const int*    mt = mg + t * 32;

        bf16x8 kf[4];
#pragma unroll
        for (int dc = 0; dc < 4; ++dc)
            kf[dc] = *(const bf16x8*)&kr[dc * 512u + lane * 8u];

        f32x16 s = {0,0,0,0,0,0,0,0,0,0,0,0,0,0,0,0};
        __builtin_amdgcn_s_setprio(1);
#pragma unroll
        for (int dc = 0; dc < 4; ++dc)
            s = __builtin_amdgcn_mfma_f32_32x32x16_bf16(kf[dc], qf[dc], s, 0, 0, 0);
        __builtin_amdgcn_s_setprio(0);

        // mask post-MFMA (r7-proven), direct int4 loads (L1-hot 8KB region)
        float p[16];
#pragma unroll
        for (int r1 = 0; r1 < 4; ++r1) {
            int4 mv = *(const int4*)(mt + r1 * 8 + hi * 4);
            p[r1 * 4 + 0] = exp2_fast(mv.x ? s[r1 * 4 + 0] : -1e30f);
            p[r1 * 4 + 1] = exp2_fast(mv.y ? s[r1 * 4 + 1] : -1e30f);
            p[r1 * 4 + 2] = exp2_fast(mv.z ? s[r1 * 4 + 2] : -1e30f);
            p[r1 * 4 + 3] = exp2_fast(mv.w ? s[r1 * 4 + 3] : -1e30f);
            ls0 += p[r1 * 4 + 0]; ls1 += p[r1 * 4 + 1];
            ls2 += p[r1 * 4 + 2]; ls3 += p[r1 * 4 + 3];
        }

        // pack P -> PV A-frags: cvt_pk + permlane32_swap (r9/r10-proven)
#pragma unroll
        for (int c = 0; c < 2; ++c) {
            unsigned a0 = cvtpk_bf16(p[8 * c + 0], p[8 * c + 1]);
            unsigned a1 = cvtpk_bf16(p[8 * c + 2], p[8 * c + 3]);
            unsigned b0 = cvtpk_bf16(p[8 * c + 4], p[8 * c + 5]);
            unsigned b1 = cvtpk_bf16(p[8 * c + 6], p[8 * c + 7]);
            asm("v_permlane32_swap_b32 %0, %1" : "+v"(a0), "+v"(b0));
            asm("v_permlane32_swap_b32 %0, %1" : "+v"(a1), "+v"(b1));
            union { unsigned w[4]; bf16x8 v; } pa;
            pa.w[0] = a0; pa.w[1] = a1; pa.w[2] = b0; pa.w[3] = b1;
            // V fragments: direct global reads (frag-order, L2/L3-hot)
            bf16x8 vf0 = *(const bf16x8*)(vt + (c * 2 + 0) * 512u);
            bf16x8 vf1 = *(const bf16x8*)(vt + (c * 2 + 1) * 512u);
            __builtin_amdgcn_s_setprio(1);
            oacc0 = __builtin_amdgcn_mfma_f32_32x32x16_bf16(pa.v, vf0, oacc0, 0, 0, 0);
            oacc1 = __builtin_amdgcn_mfma_f32_32x32x16_bf16(pa.v, vf1, oacc1, 0, 0, 0);
            __builtin_amdgcn_s_setprio(0);
        }

        asm volatile("s_waitcnt vmcnt(0)" ::: "memory");
        __syncthreads();
        pb ^= 1u;
    }
#undef STAGE

    // denominator: lane's 16 rows + xor-32 partner's rows = tile's 32 keys
    float lsum = (ls0 + ls1) + (ls2 + ls3);
    lsum += __shfl_xor(lsum, 32);

    // ---- 4-way kgrp combine (r11-proven-correct), overlaying K LDS ----
    if (kgrp == 3) {
#pragma unroll
        for (int r = 0; r < 16; ++r) {
            sm.c.ob[qsub][r][lane]      = oacc0[r];
            sm.c.ob[qsub][16 + r][lane] = oacc1[r];
        }
        sm.c.lsb[qsub][lane] = lsum;
    }
    __syncthreads();
    if (kgrp == 2) {
#pragma unroll
        for (int r = 0; r < 16; ++r) {
            sm.c.ob[qsub][r][lane]      += oacc0[r];
            sm.c.ob[qsub][16 + r][lane] += oacc1[r];
        }
        sm.c.lsb[qsub][lane] += lsum;
    }
    __syncthreads();
    if (kgrp == 1) {
#pragma unroll
        for (int r = 0; r < 16; ++r) {
            sm.c.ob[qsub][r][lane]      += oacc0[r];
            sm.c.ob[qsub][16 + r][lane] += oacc1[r];
        }
        sm.c.lsb[qsub][lane] += lsum;
    }
    __syncthreads();
    if (kgrp == 0) {
        lsum += sm.c.lsb[qsub][lane];
#pragma unroll
        for (int r = 0; r < 16; ++r) {
            oacc0[r] += sm.c.ob[qsub][r][lane];
            oacc1[r] += sm.c.ob[qsub][16 + r][lane];
        }
        if (hi == 0) sm.c.rls[qsub][l31] = 1.0f / lsum;
#pragma unroll
        for (int r1 = 0; r1 < 4; ++r1) {
#pragma unroll
            for (int r0 = 0; r0 < 4; ++r0) {
                const int reg = r1 * 4 + r0;
                const unsigned q = r0 + 8u * r1 + 4u * hi;
                const float rr = sm.c.rls[qsub][q];
                float* ob = outp + (((size_t)(b * S_LEN) + q0 + q) * NH + h) * HD + l31;
                ob[0]  = oacc0[reg] * rr;
                ob[32] = oacc1[reg] * rr;
            }
        }
    }
}

extern "C" void kernel_launch(void* const* d_in, const int* in_sizes, int n_in,
                              void* d_out, int out_size, void* d_ws, size_t ws_size,
                              hipStream_t stream) {
    const float* Qp = (const float*)d_in[0];
    const float* Kp = (const float*)d_in[1];
    const float* Vp = (const float*)d_in[2];
    const int* maskp = (const int*)d_in[3];
    float* outp = (float*)d_out;

    ushort* Kws = (ushort*)d_ws;                              // 8.39 MB frag-order K
    ushort* Vws = Kws + (size_t)2 * NH * S_LEN * HD;          // 8.39 MB frag-order V^T

    hipLaunchKernelGGL(prep_k_kernel, dim3(2048), dim3(256), 0, stream, Kp, Kws);
    hipLaunchKernelGGL(prep_v_kernel, dim3(32, 32), dim3(256), 0, stream, Vp, Vws);
    hipLaunchKernelGGL(attn_kernel, dim3(S_LEN / 64, 32), dim3(512), 0, stream,
                       Qp, Kws, Vws, maskp, outp);
}

// Round 14
// 66.489 us; speedup vs baseline: 4.3306x; 1.3249x over previous
//
#include <hip/hip_runtime.h>
#include <hip/hip_bf16.h>

#define S_LEN 2048
#define NH 16
#define HD 64

typedef __attribute__((ext_vector_type(8))) __bf16 bf16x8;
typedef __attribute__((ext_vector_type(16))) float f32x16;

// 0.125 (1/sqrt(64)) * log2(e): folded into Q so softmax uses exp2 directly
#define QSCALE 0.1803368801111204f

static __device__ __forceinline__ ushort f2bf(float f) {
    unsigned int u = __float_as_uint(f);
    u += 0x7fffu + ((u >> 16) & 1u);
    return (ushort)(u >> 16);
}

static __device__ __forceinline__ void gload16(const void* g, void* l) {
    __builtin_amdgcn_global_load_lds(
        (const __attribute__((address_space(1))) unsigned int*)g,
        (__attribute__((address_space(3))) unsigned int*)l, 16, 0, 0);
}
static __device__ __forceinline__ void gload4(const void* g, void* l) {
    __builtin_amdgcn_global_load_lds(
        (const __attribute__((address_space(1))) unsigned int*)g,
        (__attribute__((address_space(3))) unsigned int*)l, 4, 0, 0);
}

static __device__ __forceinline__ unsigned cvtpk_bf16(float lo, float hi) {
    unsigned r;
    asm("v_cvt_pk_bf16_f32 %0, %1, %2" : "=v"(r) : "v"(lo), "v"(hi));
    return r;
}
static __device__ __forceinline__ float exp2_fast(float x) {
    float r;
    asm("v_exp_f32 %0, %1" : "=v"(r) : "v"(x));
    return r;
}

// ---------------------------------------------------------------------------
// K prepass: [B,S,H,D] f32 -> frag-order bf16.  (r2/r7-proven, verbatim)
// ---------------------------------------------------------------------------
__global__ __launch_bounds__(256) void prep_k_kernel(const float* __restrict__ in,
                                                     ushort* __restrict__ out) {
    unsigned t = blockIdx.x * 256u + threadIdx.x;   // 524288 total
    unsigned o = t & 7u;            // d-octet
    unsigned s = (t >> 3) & 2047u;
    unsigned bh = t >> 14;
    unsigned b = bh >> 4, h = bh & 15u;
    const float* src = in + (((size_t)(b * S_LEN) + s) * NH + h) * HD + o * 8;
    float4 x = *(const float4*)src;
    float4 y = *(const float4*)(src + 4);
    union { ushort u[8]; uint4 q; } fu;
    fu.u[0] = f2bf(x.x); fu.u[1] = f2bf(x.y); fu.u[2] = f2bf(x.z); fu.u[3] = f2bf(x.w);
    fu.u[4] = f2bf(y.x); fu.u[5] = f2bf(y.y); fu.u[6] = f2bf(y.z); fu.u[7] = f2bf(y.w);
    unsigned kt = s >> 6, kh = (s >> 5) & 1u, kl = s & 31u;
    unsigned dchunk = o >> 1, ho = o & 1u;
    size_t ci = (((size_t)(bh * 32u + kt) * 2u + kh) * 4u + dchunk) * 64u + kl + 32u * ho;
    *(uint4*)(out + ci * 8u) = fu.q;
}

// ---------------------------------------------------------------------------
// V prepass: [B,S,H,D] f32 -> frag-order V^T bf16.  (r2/r7-proven, verbatim)
// ---------------------------------------------------------------------------
__global__ __launch_bounds__(256) void prep_v_kernel(const float* __restrict__ in,
                                                     ushort* __restrict__ out) {
    __shared__ float T[64][68];
    const unsigned tid = threadIdx.x;
    const unsigned kt = blockIdx.x, bh = blockIdx.y;
    const unsigned b = bh >> 4, h = bh & 15u;
#pragma unroll
    for (int i = 0; i < 4; ++i) {
        unsigned idx = tid + i * 256u;
        unsigned sl = idx >> 4, d4 = (idx & 15u) * 4u;
        float4 v = *(const float4*)(in + (((size_t)(b * S_LEN) + kt * 64u + sl) * NH + h) * HD + d4);
        *(float4*)&T[sl][d4] = v;
    }
    __syncthreads();
#pragma unroll
    for (int it = 0; it < 2; ++it) {
        unsigned ct = tid + it * 256u;
        unsigned l = ct & 63u, sub = ct >> 6;
        unsigned nt = sub & 1u, c = (sub >> 1) & 1u, kh = sub >> 2;
        unsigned d = (l & 31u) + 32u * nt;
        unsigned kb = kh * 32u + c * 16u + (l >> 5) * 8u;
        union { ushort u[8]; uint4 q; } fu;
#pragma unroll
        for (int j = 0; j < 8; ++j) fu.u[j] = f2bf(T[kb + j][d]);
        *(uint4*)(out + ((size_t)(bh * 32u + kt) * 8u + sub) * 512u + l * 8u) = fu.q;
    }
}

// ---------------------------------------------------------------------------
// Flash attention: r10 base (best, 55.7us) + three cuts:
//  1. lsum via ones-MFMA (oacc2): kills 32 VALU adds/tile + shfl + rls LDS
//  2. kh software-pipeline: QK(kh1) issued between softmax(kh0) and PV(kh0)
//  3. mask pre-staged in prologue (8KB LDS), STAGE uniform 4 ops
// 8 waves (4 qsub x 2 kgrp), KBLK=64, K+V LDS double-buffered (gload_lds),
// vmcnt(0) drain per tile, permlane32_swap pack, post-MFMA cndmask
// (C-init BANNED), launch_bounds(512,4) (>=6 BANNED: allocator meltdown).
// ---------------------------------------------------------------------------
struct TileMem {
    ushort K[2][2][4096];   // [kgrp][pb] 32 KB
    ushort V[2][2][4096];   // 32 KB
    int    mk[2][1024];     // 8 KB: full mask per kgrp (1024 keys)
};
struct CombMem {
    float ob[4][32][64];    // 32 KB
    float ls2[4][16][64];   // 16 KB (oacc2 rows)
};
union SMemU { TileMem s; CombMem c; };

__global__ __launch_bounds__(512, 4) void attn_kernel(const float* __restrict__ Qp,
                                                      const ushort* __restrict__ Kws,
                                                      const ushort* __restrict__ Vws,
                                                      const int* __restrict__ maskp,
                                                      float* __restrict__ outp) {
    __shared__ __align__(16) SMemU sm;

    const unsigned tid = threadIdx.x;
    const unsigned wid = tid >> 6;
    const unsigned lane = tid & 63u;
    const unsigned l31 = lane & 31u;
    const unsigned hi = lane >> 5;
    const unsigned qsub = wid & 3u;
    const unsigned kgrp = wid >> 2;

    const unsigned bh = blockIdx.y;
    const unsigned b = bh >> 4, h = bh & 15u;
    const unsigned q0 = blockIdx.x * 128u + qsub * 32u;

    // Q fragments (B-operand of swapped QK^T): lane holds Q[q0+l31][16dc+8hi+j]
    bf16x8 qf[4];
    {
        const float* qb = Qp + (((size_t)(b * S_LEN) + q0 + l31) * NH + h) * HD + hi * 8u;
#pragma unroll
        for (int dc = 0; dc < 4; ++dc) {
            float4 x = *(const float4*)(qb + dc * 16);
            float4 y = *(const float4*)(qb + dc * 16 + 4);
            union { ushort u[8]; bf16x8 v; } fu;
            fu.u[0] = f2bf(x.x * QSCALE); fu.u[1] = f2bf(x.y * QSCALE);
            fu.u[2] = f2bf(x.z * QSCALE); fu.u[3] = f2bf(x.w * QSCALE);
            fu.u[4] = f2bf(y.x * QSCALE); fu.u[5] = f2bf(y.y * QSCALE);
            fu.u[6] = f2bf(y.z * QSCALE); fu.u[7] = f2bf(y.w * QSCALE);
            qf[dc] = fu.v;
        }
    }

    // ones B-fragment for the lsum MFMA
    bf16x8 one8;
    {
        union { ushort u[8]; bf16x8 v; } ou;
#pragma unroll
        for (int j = 0; j < 8; ++j) ou.u[j] = 0x3F80;
        one8 = ou.v;
    }

    f32x16 oacc0 = {0,0,0,0,0,0,0,0,0,0,0,0,0,0,0,0};
    f32x16 oacc1 = {0,0,0,0,0,0,0,0,0,0,0,0,0,0,0,0};
    f32x16 oacc2 = {0,0,0,0,0,0,0,0,0,0,0,0,0,0,0,0};

    // staging pointers (per-lane), kgrp covers tiles kgrp*16..+15
    const char* kgp = (const char*)Kws + (size_t)bh * 262144u
                    + ((size_t)kgrp * 131072u) + (2u * qsub) * 1024u + lane * 16u;
    const char* vgp = (const char*)Vws + (size_t)bh * 262144u
                    + ((size_t)kgrp * 131072u) + (2u * qsub) * 1024u + lane * 16u;

    ushort* klb = &sm.s.K[kgrp][0][2u * qsub * 512u];
    ushort* vlb = &sm.s.V[kgrp][0][2u * qsub * 512u];
    const ushort* krd = &sm.s.K[kgrp][0][0];
    const ushort* vrd = &sm.s.V[kgrp][0][0];

#define STAGE(I, PB) do {                                                      \
    const size_t toff = (size_t)(I) * 8192u;                                   \
    gload16(kgp + toff,          klb + (PB) * 4096u);                          \
    gload16(kgp + toff + 1024u,  klb + (PB) * 4096u + 512u);                   \
    gload16(vgp + toff,          vlb + (PB) * 4096u);                          \
    gload16(vgp + toff + 1024u,  vlb + (PB) * 4096u + 512u);                   \
  } while (0)

    // prologue: stage full mask for this kgrp (each wave a 256-int slice)
    {
        const int* mgp = maskp + (size_t)b * S_LEN + kgrp * 1024u + qsub * 256u + lane;
#pragma unroll
        for (int j = 0; j < 4; ++j)
            gload4(mgp + j * 64, &sm.s.mk[kgrp][qsub * 256u + j * 64u]);
    }
    STAGE(0, 0u);
    asm volatile("s_waitcnt vmcnt(0)" ::: "memory");
    __syncthreads();

    unsigned pb = 0;
    for (int i = 0; i < 16; ++i) {
        if (i < 15) STAGE(i + 1, pb ^ 1u);
        const ushort* kr = krd + pb * 4096u;
        const ushort* vr = vrd + pb * 4096u;
        const int*    mr = &sm.s.mk[kgrp][(unsigned)i * 64u];

        // ---- QK kh0 ----
        bf16x8 kfa[4];
#pragma unroll
        for (int dc = 0; dc < 4; ++dc)
            kfa[dc] = *(const bf16x8*)&kr[dc * 512u + lane * 8u];
        f32x16 s0 = {0,0,0,0,0,0,0,0,0,0,0,0,0,0,0,0};
        __builtin_amdgcn_s_setprio(1);
#pragma unroll
        for (int dc = 0; dc < 4; ++dc)
            s0 = __builtin_amdgcn_mfma_f32_32x32x16_bf16(kfa[dc], qf[dc], s0, 0, 0, 0);
        __builtin_amdgcn_s_setprio(0);

        // ---- softmax kh0 (stalls on s0) ----
        float p[16];
#pragma unroll
        for (int r1 = 0; r1 < 4; ++r1) {
            int mv[4];
            *(int4*)mv = *(const int4*)&mr[r1 * 8 + hi * 4];
#pragma unroll
            for (int r0 = 0; r0 < 4; ++r0) {
                const int reg = r1 * 4 + r0;
                p[reg] = exp2_fast(mv[r0] ? s0[reg] : -1e30f);
            }
        }

        // ---- QK kh1 issued here: latency hides under kh0 pack+PV ----
        bf16x8 kfb[4];
#pragma unroll
        for (int dc = 0; dc < 4; ++dc)
            kfb[dc] = *(const bf16x8*)&kr[(4 + dc) * 512u + lane * 8u];
        f32x16 s1 = {0,0,0,0,0,0,0,0,0,0,0,0,0,0,0,0};
        __builtin_amdgcn_s_setprio(1);
#pragma unroll
        for (int dc = 0; dc < 4; ++dc)
            s1 = __builtin_amdgcn_mfma_f32_32x32x16_bf16(kfb[dc], qf[dc], s1, 0, 0, 0);
        __builtin_amdgcn_s_setprio(0);

        // ---- pack + PV kh0 (overlaps s1's MFMAs) ----
#pragma unroll
        for (int c = 0; c < 2; ++c) {
            unsigned a0 = cvtpk_bf16(p[8 * c + 0], p[8 * c + 1]);
            unsigned a1 = cvtpk_bf16(p[8 * c + 2], p[8 * c + 3]);
            unsigned b0 = cvtpk_bf16(p[8 * c + 4], p[8 * c + 5]);
            unsigned b1 = cvtpk_bf16(p[8 * c + 6], p[8 * c + 7]);
            asm("v_permlane32_swap_b32 %0, %1" : "+v"(a0), "+v"(b0));
            asm("v_permlane32_swap_b32 %0, %1" : "+v"(a1), "+v"(b1));
            union { unsigned w[4]; bf16x8 v; } pa;
            pa.w[0] = a0; pa.w[1] = a1; pa.w[2] = b0; pa.w[3] = b1;
            bf16x8 vf0 = *(const bf16x8*)&vr[(c * 2 + 0) * 512u + lane * 8u];
            bf16x8 vf1 = *(const bf16x8*)&vr[(c * 2 + 1) * 512u + lane * 8u];
            __builtin_amdgcn_s_setprio(1);
            oacc0 = __builtin_amdgcn_mfma_f32_32x32x16_bf16(pa.v, vf0, oacc0, 0, 0, 0);
            oacc1 = __builtin_amdgcn_mfma_f32_32x32x16_bf16(pa.v, vf1, oacc1, 0, 0, 0);
            oacc2 = __builtin_amdgcn_mfma_f32_32x32x16_bf16(pa.v, one8, oacc2, 0, 0, 0);
            __builtin_amdgcn_s_setprio(0);
        }

        // ---- softmax kh1 (s1 long done) ----
#pragma unroll
        for (int r1 = 0; r1 < 4; ++r1) {
            int mv[4];
            *(int4*)mv = *(const int4*)&mr[32 + r1 * 8 + hi * 4];
#pragma unroll
            for (int r0 = 0; r0 < 4; ++r0) {
                const int reg = r1 * 4 + r0;
                p[reg] = exp2_fast(mv[r0] ? s1[reg] : -1e30f);
            }
        }

        // ---- pack + PV kh1 ----
#pragma unroll
        for (int c = 0; c < 2; ++c) {
            unsigned a0 = cvtpk_bf16(p[8 * c + 0], p[8 * c + 1]);
            unsigned a1 = cvtpk_bf16(p[8 * c + 2], p[8 * c + 3]);
            unsigned b0 = cvtpk_bf16(p[8 * c + 4], p[8 * c + 5]);
            unsigned b1 = cvtpk_bf16(p[8 * c + 6], p[8 * c + 7]);
            asm("v_permlane32_swap_b32 %0, %1" : "+v"(a0), "+v"(b0));
            asm("v_permlane32_swap_b32 %0, %1" : "+v"(a1), "+v"(b1));
            union { unsigned w[4]; bf16x8 v; } pa;
            pa.w[0] = a0; pa.w[1] = a1; pa.w[2] = b0; pa.w[3] = b1;
            bf16x8 vf0 = *(const bf16x8*)&vr[((2 + c) * 2 + 0) * 512u + lane * 8u];
            bf16x8 vf1 = *(const bf16x8*)&vr[((2 + c) * 2 + 1) * 512u + lane * 8u];
            __builtin_amdgcn_s_setprio(1);
            oacc0 = __builtin_amdgcn_mfma_f32_32x32x16_bf16(pa.v, vf0, oacc0, 0, 0, 0);
            oacc1 = __builtin_amdgcn_mfma_f32_32x32x16_bf16(pa.v, vf1, oacc1, 0, 0, 0);
            oacc2 = __builtin_amdgcn_mfma_f32_32x32x16_bf16(pa.v, one8, oacc2, 0, 0, 0);
            __builtin_amdgcn_s_setprio(0);
        }

        asm volatile("s_waitcnt vmcnt(0)" ::: "memory");
        __syncthreads();
        pb ^= 1u;
    }
#undef STAGE

    // ---- combine the two key-groups (LDS overlays the dead tile buffers) ----
    // oacc2[reg] = lsum for q-row crow(reg,hi) -- same row map as oacc0/1.
    if (kgrp == 1) {
#pragma unroll
        for (int r = 0; r < 16; ++r) {
            sm.c.ob[qsub][r][lane]      = oacc0[r];
            sm.c.ob[qsub][16 + r][lane] = oacc1[r];
            sm.c.ls2[qsub][r][lane]     = oacc2[r];
        }
    }
    __syncthreads();
    if (kgrp == 0) {
#pragma unroll
        for (int r = 0; r < 16; ++r) {
            oacc0[r] += sm.c.ob[qsub][r][lane];
            oacc1[r] += sm.c.ob[qsub][16 + r][lane];
            oacc2[r] += sm.c.ls2[qsub][r][lane];
        }
#pragma unroll
        for (int r1 = 0; r1 < 4; ++r1) {
#pragma unroll
            for (int r0 = 0; r0 < 4; ++r0) {
                const int reg = r1 * 4 + r0;
                const unsigned q = r0 + 8u * r1 + 4u * hi;
                const float rr = 1.0f / oacc2[reg];
                float* ob = outp + (((size_t)(b * S_LEN) + q0 + q) * NH + h) * HD + l31;
                ob[0]  = oacc0[reg] * rr;
                ob[32] = oacc1[reg] * rr;
            }
        }
    }
}

extern "C" void kernel_launch(void* const* d_in, const int* in_sizes, int n_in,
                              void* d_out, int out_size, void* d_ws, size_t ws_size,
                              hipStream_t stream) {
    const float* Qp = (const float*)d_in[0];
    const float* Kp = (const float*)d_in[1];
    const float* Vp = (const float*)d_in[2];
    const int* maskp = (const int*)d_in[3];
    float* outp = (float*)d_out;

    ushort* Kws = (ushort*)d_ws;                              // 8.39 MB frag-order K
    ushort* Vws = Kws + (size_t)2 * NH * S_LEN * HD;          // 8.39 MB frag-order V^T

    hipLaunchKernelGGL(prep_k_kernel, dim3(2048), dim3(256), 0, stream, Kp, Kws);
    hipLaunchKernelGGL(prep_v_kernel, dim3(32, 32), dim3(256), 0, stream, Vp, Vws);
    hipLaunchKernelGGL(attn_kernel, dim3(S_LEN / 128, 32), dim3(512), 0, stream,
                       Qp, Kws, Vws, maskp, outp);
}